// Round 6
// baseline (358.161 us; speedup 1.0000x reference)
//
#include <hip/hip_runtime.h>
#include <hip/hip_bf16.h>

#define HID 256
#define NN 8192
#define NE 262144

typedef float f32x4 __attribute__((ext_vector_type(4)));
typedef __bf16 bf16x8 __attribute__((ext_vector_type(8)));
typedef __bf16 bf16x4 __attribute__((ext_vector_type(4)));

// ---------------- weight conversion: f32 -> bf16, [Wq][Wk][Wv][We] ----------------
__global__ void conv_weights(const float* __restrict__ wq, const float* __restrict__ wk,
                             const float* __restrict__ wv, const float* __restrict__ we,
                             __bf16* __restrict__ o) {
    int i = blockIdx.x * 256 + threadIdx.x;
    const float* srcs[4] = {wq, wk, wv, we};
    int m = i >> 16;
    int j = i & 65535;
    o[i] = (__bf16)srcs[m][j];
}

// stage a 64x256 f32 tile into bf16 LDS, XOR-swizzled rows
__device__ __forceinline__ void stage_tile(const float* __restrict__ src, char* lb, int tid) {
    const float4* xs = (const float4*)src;
    #pragma unroll
    for (int kq = 0; kq < 16; ++kq) {
        int f = tid + kq * 256;
        int row = f >> 6, c4 = f & 63;
        float4 v = xs[f];
        bf16x4 h;
        h[0] = (__bf16)v.x; h[1] = (__bf16)v.y; h[2] = (__bf16)v.z; h[3] = (__bf16)v.w;
        int off = (row * 512 + c4 * 8) ^ ((row & 7) << 4);
        *(bf16x4*)(lb + off) = h;
    }
}

// ---------------- QKV projection: Q/K/V = x @ W^T + b, output bf16 ----------------
__global__ void qkv_gemm(const float* __restrict__ x,
                         const __bf16* __restrict__ wbf,
                         const float* __restrict__ bq, const float* __restrict__ bk,
                         const float* __restrict__ bv,
                         __bf16* __restrict__ qbf, __bf16* __restrict__ kbf,
                         __bf16* __restrict__ vbf) {
    __shared__ __bf16 xt[64 * 256];
    char* lb = (char*)xt;
    int tid = threadIdx.x;
    int blk = blockIdx.x;

    stage_tile(x + (size_t)blk * 64 * 256, lb, tid);
    __syncthreads();

    int w = tid >> 6, lane = tid & 63;
    int l15 = lane & 15, l4 = lane >> 4;
    int cw = w * 64;
    const float* biases[3] = {bq, bk, bv};
    __bf16* outs[3] = {qbf, kbf, vbf};

    for (int m = 0; m < 3; ++m) {
        const __bf16* W = wbf + (size_t)m * 65536;
        f32x4 acc[4][4] = {};
        for (int ks = 0; ks < 8; ++ks) {
            bf16x8 aW[4], bE[4];
            #pragma unroll
            for (int tn = 0; tn < 4; ++tn)
                aW[tn] = *(const bf16x8*)(W + (size_t)(cw + tn * 16 + l15) * 256 + ks * 32 + l4 * 8);
            #pragma unroll
            for (int te = 0; te < 4; ++te) {
                int row = te * 16 + l15;
                int off = (row * 512 + ks * 64 + l4 * 16) ^ ((row & 7) << 4);
                bE[te] = *(const bf16x8*)(lb + off);
            }
            #pragma unroll
            for (int tn = 0; tn < 4; ++tn)
                #pragma unroll
                for (int te = 0; te < 4; ++te)
                    acc[tn][te] = __builtin_amdgcn_mfma_f32_16x16x32_bf16(aW[tn], bE[te], acc[tn][te], 0, 0, 0);
        }
        __bf16* out = outs[m];
        #pragma unroll
        for (int tn = 0; tn < 4; ++tn) {
            float4 b4 = *(const float4*)(biases[m] + cw + tn * 16 + l4 * 4);
            #pragma unroll
            for (int te = 0; te < 4; ++te) {
                int row = blk * 64 + te * 16 + l15;
                int col = cw + tn * 16 + l4 * 4;
                bf16x4 h;
                h[0] = (__bf16)(acc[tn][te][0] + b4.x);
                h[1] = (__bf16)(acc[tn][te][1] + b4.y);
                h[2] = (__bf16)(acc[tn][te][2] + b4.z);
                h[3] = (__bf16)(acc[tn][te][3] + b4.w);
                *(bf16x4*)(out + (size_t)row * 256 + col) = h;
            }
        }
    }
}

// ---------------- counting sort by destination key = b*NN + s ---------------------
__global__ void k_hist(const int* __restrict__ eidx, unsigned* __restrict__ hist) {
    int e = blockIdx.x * 256 + threadIdx.x;
    int key = eidx[e] * NN + eidx[NE + e];
    atomicAdd(&hist[key], 1u);
}

__global__ void k_scan(const unsigned* __restrict__ hist, unsigned* __restrict__ cursor) {
    __shared__ unsigned tot[256];
    int tid = threadIdx.x;
    unsigned s = 0;
    for (int i = 0; i < 64; ++i) s += hist[tid * 64 + i];
    tot[tid] = s;
    __syncthreads();
    for (int d = 1; d < 256; d <<= 1) {
        unsigned v = (tid >= d) ? tot[tid - d] : 0u;
        __syncthreads();
        tot[tid] += v;
        __syncthreads();
    }
    unsigned run = (tid == 0) ? 0u : tot[tid - 1];
    for (int i = 0; i < 64; ++i) {
        int idx = tid * 64 + i;
        cursor[idx] = run;
        run += hist[idx];
    }
}

__global__ void k_perm(const int* __restrict__ eidx, unsigned* __restrict__ cursor,
                       int* __restrict__ perm) {
    int e = blockIdx.x * 256 + threadIdx.x;
    int key = eidx[e] * NN + eidx[NE + e];
    unsigned pos = atomicAdd(&cursor[key], 1u);
    perm[pos] = e;
}

// -------- fused edge kernel: Ke MFMA -> logits(frag) -> softmax -> Ve MFMA --------
// --------        -> run-length sorted scatter. One ev read total.          --------
__global__ __launch_bounds__(256, 4)
void edge_fused(const float* __restrict__ ev,
                const int* __restrict__ eidx,
                const __bf16* __restrict__ wbf,
                const float* __restrict__ bkb, const float* __restrict__ beb,
                const __bf16* __restrict__ qbf, const __bf16* __restrict__ kbf,
                const __bf16* __restrict__ vbf,
                const int* __restrict__ perm,
                float* __restrict__ out) {
    __shared__ __bf16 evt[64 * 256];           // ev tile, later Ve tile (32 KB)
    __shared__ int pe[64], sb[64], ss[64], st[64];
    __shared__ float smx[64 * 8];
    char* lb = (char*)evt;
    int tid = threadIdx.x;
    int p0 = blockIdx.x * 64;

    if (tid < 64) {
        int e = perm[p0 + tid];
        pe[tid] = e;
        sb[tid] = eidx[e];
        ss[tid] = eidx[NE + e];
        st[tid] = eidx[2 * NE + e];
    }
    __syncthreads();

    // stage gathered ev rows (sorted order), bf16 + XOR swizzle
    #pragma unroll
    for (int kq = 0; kq < 16; ++kq) {
        int f = tid + kq * 256;
        int row = f >> 6, c4 = f & 63;
        const float4* src = (const float4*)(ev + (size_t)pe[row] * 256);
        float4 v = src[c4];
        bf16x4 h;
        h[0] = (__bf16)v.x; h[1] = (__bf16)v.y; h[2] = (__bf16)v.z; h[3] = (__bf16)v.w;
        int off = (row * 512 + c4 * 8) ^ ((row & 7) << 4);
        *(bf16x4*)(lb + off) = h;
    }
    __syncthreads();

    int w = tid >> 6, lane = tid & 63;
    int l15 = lane & 15, l4 = lane >> 4;
    int cw = w * 64;

    // ---- pass 1: Ke = ev @ Wk^T (swapped operands; acc[tn][te]) ----
    {
        const __bf16* WK = wbf + 65536;
        f32x4 acc[4][4] = {};
        for (int ks = 0; ks < 8; ++ks) {
            bf16x8 aW[4], bE[4];
            #pragma unroll
            for (int tn = 0; tn < 4; ++tn)
                aW[tn] = *(const bf16x8*)(WK + (size_t)(cw + tn * 16 + l15) * 256 + ks * 32 + l4 * 8);
            #pragma unroll
            for (int te = 0; te < 4; ++te) {
                int row = te * 16 + l15;
                int off = (row * 512 + ks * 64 + l4 * 16) ^ ((row & 7) << 4);
                bE[te] = *(const bf16x8*)(lb + off);
            }
            #pragma unroll
            for (int tn = 0; tn < 4; ++tn)
                #pragma unroll
                for (int te = 0; te < 4; ++te)
                    acc[tn][te] = __builtin_amdgcn_mfma_f32_16x16x32_bf16(aW[tn], bE[te], acc[tn][te], 0, 0, 0);
        }

        // ---- logits directly from fragment layout ----
        // lane (l15,l4) holds edge te*16+l15, channels cw+tn*16+l4*4+r; head = w*2+(tn>>1)
        f32x4 bk4[4];
        #pragma unroll
        for (int tn = 0; tn < 4; ++tn)
            bk4[tn] = *(const f32x4*)(bkb + cw + tn * 16 + l4 * 4);

        #pragma unroll
        for (int te = 0; te < 4; ++te) {
            int el = te * 16 + l15;
            int b_ = sb[el], s_ = ss[el], t_ = st[el];
            const __bf16* qp = qbf + ((size_t)b_ * NN + s_) * 256 + cw + l4 * 4;
            const __bf16* kp = kbf + ((size_t)b_ * NN + t_) * 256 + cw + l4 * 4;
            bf16x4 qv[4], kv[4];
            #pragma unroll
            for (int tn = 0; tn < 4; ++tn) {
                qv[tn] = *(const bf16x4*)(qp + tn * 16);
                kv[tn] = *(const bf16x4*)(kp + tn * 16);
            }
            #pragma unroll
            for (int h = 0; h < 2; ++h) {
                float val = 0.f;
                #pragma unroll
                for (int j = 0; j < 2; ++j) {
                    int tn = h * 2 + j;
                    #pragma unroll
                    for (int r = 0; r < 4; ++r) {
                        float ke = acc[tn][te][r] + bk4[tn][r];
                        val += (float)qv[tn][r] * ((float)kv[tn][r] + ke);
                    }
                }
                val += __shfl_xor(val, 16);
                val += __shfl_xor(val, 32);          // sum over the 4 l4 lane-groups
                if (l4 == 0) smx[el * 8 + w * 2 + h] = val * 0.17677669529663687f;
            }
        }
    }
    __syncthreads();

    // ---- softmax over 8 heads per edge ----
    if (tid < 64) {
        float l[8], mx = -1e30f;
        #pragma unroll
        for (int h = 0; h < 8; ++h) { l[h] = smx[tid * 8 + h]; mx = fmaxf(mx, l[h]); }
        float sum = 0.f;
        #pragma unroll
        for (int h = 0; h < 8; ++h) { l[h] = __expf(l[h] - mx); sum += l[h]; }
        float inv = 1.f / sum;
        #pragma unroll
        for (int h = 0; h < 8; ++h) smx[tid * 8 + h] = l[h] * inv;
    }

    // ---- pass 2: Ve = ev @ We^T (reuses evt; acc registers recycled) ----
    {
        const __bf16* WE = wbf + 3 * 65536;
        f32x4 acc[4][4] = {};
        for (int ks = 0; ks < 8; ++ks) {
            bf16x8 aW[4], bE[4];
            #pragma unroll
            for (int tn = 0; tn < 4; ++tn)
                aW[tn] = *(const bf16x8*)(WE + (size_t)(cw + tn * 16 + l15) * 256 + ks * 32 + l4 * 8);
            #pragma unroll
            for (int te = 0; te < 4; ++te) {
                int row = te * 16 + l15;
                int off = (row * 512 + ks * 64 + l4 * 16) ^ ((row & 7) << 4);
                bE[te] = *(const bf16x8*)(lb + off);
            }
            #pragma unroll
            for (int tn = 0; tn < 4; ++tn)
                #pragma unroll
                for (int te = 0; te < 4; ++te)
                    acc[tn][te] = __builtin_amdgcn_mfma_f32_16x16x32_bf16(aW[tn], bE[te], acc[tn][te], 0, 0, 0);
        }
        __syncthreads();   // all evt reads (and smx softmax) done

        // Ve (+bias) -> LDS bf16, edge-swizzled (overwrites evt)
        #pragma unroll
        for (int tn = 0; tn < 4; ++tn) {
            float4 b4 = *(const float4*)(beb + cw + tn * 16 + l4 * 4);
            #pragma unroll
            for (int te = 0; te < 4; ++te) {
                int edge = te * 16 + l15;
                int colb = (cw + tn * 16 + l4 * 4) * 2;
                bf16x4 h;
                h[0] = (__bf16)(acc[tn][te][0] + b4.x);
                h[1] = (__bf16)(acc[tn][te][1] + b4.y);
                h[2] = (__bf16)(acc[tn][te][2] + b4.z);
                h[3] = (__bf16)(acc[tn][te][3] + b4.w);
                int off = (edge * 512 + colb) ^ ((edge & 7) << 4);
                *(bf16x4*)(lb + off) = h;
            }
        }
    }
    __syncthreads();

    // ---- tail: wave-per-edge, sorted run-length accumulate, coalesced atomics ----
    float a0 = 0.f, a1 = 0.f, a2 = 0.f, a3 = 0.f;
    int havekey = -1;
    size_t obase = 0;
    #pragma unroll
    for (int it = 0; it < 16; ++it) {
        int e = w * 16 + it;
        int b_ = sb[e], s_ = ss[e], t_ = st[e];
        const __bf16* vrow = vbf + ((size_t)b_ * NN + t_) * 256;
        int swz = (e & 7) << 4;
        float c0, c1, c2, c3;
        {
            float att, vv, vev;
            int col, off;
            col = lane;             att = smx[e * 8 + 0 + (lane >> 5)];
            vv = (float)vrow[col];  off = (e * 512 + col * 2) ^ swz;
            vev = (float)*(const __bf16*)(lb + off); c0 = att * (vv + vev);
            col = 64 + lane;        att = smx[e * 8 + 2 + (lane >> 5)];
            vv = (float)vrow[col];  off = (e * 512 + col * 2) ^ swz;
            vev = (float)*(const __bf16*)(lb + off); c1 = att * (vv + vev);
            col = 128 + lane;       att = smx[e * 8 + 4 + (lane >> 5)];
            vv = (float)vrow[col];  off = (e * 512 + col * 2) ^ swz;
            vev = (float)*(const __bf16*)(lb + off); c2 = att * (vv + vev);
            col = 192 + lane;       att = smx[e * 8 + 6 + (lane >> 5)];
            vv = (float)vrow[col];  off = (e * 512 + col * 2) ^ swz;
            vev = (float)*(const __bf16*)(lb + off); c3 = att * (vv + vev);
        }
        int key = __builtin_amdgcn_readfirstlane(b_ * NN + s_);
        if (key != havekey) {
            if (havekey >= 0) {
                float* orow = out + obase;
                unsafeAtomicAdd(orow + lane, a0);
                unsafeAtomicAdd(orow + 64 + lane, a1);
                unsafeAtomicAdd(orow + 128 + lane, a2);
                unsafeAtomicAdd(orow + 192 + lane, a3);
            }
            a0 = c0; a1 = c1; a2 = c2; a3 = c3;
            havekey = key;
            obase = (size_t)key * 256;
        } else {
            a0 += c0; a1 += c1; a2 += c2; a3 += c3;
        }
    }
    if (havekey >= 0) {
        float* orow = out + obase;
        unsafeAtomicAdd(orow + lane, a0);
        unsafeAtomicAdd(orow + 64 + lane, a1);
        unsafeAtomicAdd(orow + 128 + lane, a2);
        unsafeAtomicAdd(orow + 192 + lane, a3);
    }
}

extern "C" void kernel_launch(void* const* d_in, const int* in_sizes, int n_in,
                              void* d_out, int out_size, void* d_ws, size_t ws_size,
                              hipStream_t stream) {
    const float* node_states = (const float*)d_in[0];
    const int*   eidx        = (const int*)d_in[1];
    const float* ev          = (const float*)d_in[2];
    const float* Wq          = (const float*)d_in[3];
    const float* bq          = (const float*)d_in[4];
    const float* Wk          = (const float*)d_in[5];
    const float* bk          = (const float*)d_in[6];
    const float* Wv          = (const float*)d_in[7];
    const float* bv          = (const float*)d_in[8];
    const float* We          = (const float*)d_in[9];
    const float* be          = (const float*)d_in[10];
    float* out = (float*)d_out;

    char* ws = (char*)d_ws;
    __bf16*   qbf    = (__bf16*)ws;                   // 8.39 MB
    __bf16*   kbf    = (__bf16*)(ws + 8388608);       // 8.39 MB
    __bf16*   vbf    = (__bf16*)(ws + 16777216);      // 8.39 MB
    __bf16*   wbf    = (__bf16*)(ws + 25165824);      // 0.5 MB
    unsigned* hist   = (unsigned*)(ws + 25690112);    // 64 KB
    unsigned* cursor = (unsigned*)(ws + 25755648);    // 64 KB
    int*      perm   = (int*)(ws + 25821184);         // 1 MB

    hipMemsetAsync(d_out, 0, (size_t)out_size * sizeof(float), stream);
    hipMemsetAsync(hist, 0, 16384 * sizeof(unsigned), stream);
    conv_weights<<<1024, 256, 0, stream>>>(Wq, Wk, Wv, We, wbf);
    qkv_gemm<<<256, 256, 0, stream>>>(node_states, wbf, bq, bk, bv, qbf, kbf, vbf);
    k_hist<<<1024, 256, 0, stream>>>(eidx, hist);
    k_scan<<<1, 256, 0, stream>>>(hist, cursor);
    k_perm<<<1024, 256, 0, stream>>>(eidx, cursor, perm);
    edge_fused<<<4096, 256, 0, stream>>>(ev, eidx, wbf, bk, be, qbf, kbf, vbf, perm, out);
}